// Round 7
// baseline (336.609 us; speedup 1.0000x reference)
//
#include <hip/hip_runtime.h>
#include <hip/hip_bf16.h>

#define B_ 32
#define F_ 64
#define N_ 512
#define T_ 64

typedef __attribute__((ext_vector_type(8))) short bf16x8;
typedef __attribute__((ext_vector_type(4))) float f32x4;

__device__ __forceinline__ unsigned short f2bf(float f) {
  union { float f; unsigned int u; } v; v.f = f;
  unsigned int u = v.u;
  unsigned int r = (u + 0x7FFFu + ((u >> 16) & 1u)) >> 16;
  return (unsigned short)r;
}

// Pass 1 over x. Block=(b, 8-n chunk), 2048 blocks x 4 waves -> 32 waves/CU.
// Wave w owns f in [16w,16w+16). Lane: n_sub=lane>>4 (covers n = i*4+n_sub, i=0..1),
// t0=(lane&15)*4.
//   rhs[b,n,t]       = sum_f U3[f]*x[b,f,n,t]   (cross-wave LDS reduce)
//   t1part[b,nc,f,t] = sum_{n in chunk} U1[n]*x (shuffle-reduced partial, 64 chunks)
__global__ __launch_bounds__(256, 8) void k1_reduce(const float* __restrict__ x,
    const float* __restrict__ U1, const float* __restrict__ U3,
    float* __restrict__ t1part, float* __restrict__ rhs) {
  const int b = blockIdx.x;
  const int nc = blockIdx.y;
  const int n0 = nc * 8;
  const int tid = threadIdx.x;
  const int w = tid >> 6;
  const int lane = tid & 63;
  const int n_sub = lane >> 4;
  const int t0 = (lane & 15) * 4;

  __shared__ float lds[4][512];  // [wave][8n*64t] = 8 KB

  const float* xb = x + (size_t)b * (F_ * (size_t)N_ * T_);

  float u1c[2];
#pragma unroll
  for (int i = 0; i < 2; ++i) u1c[i] = U1[n0 + i * 4 + n_sub];

  float racc[2][4];
#pragma unroll
  for (int i = 0; i < 2; ++i)
#pragma unroll
    for (int k = 0; k < 4; ++k) racc[i][k] = 0.f;

#pragma unroll
  for (int j = 0; j < 16; ++j) {
    const int f = w * 16 + j;
    const float u3 = U3[f];
    const float* xf = xb + (size_t)f * (N_ * T_) + (size_t)n0 * T_ + n_sub * T_ + t0;
    float p0 = 0.f, p1 = 0.f, p2 = 0.f, p3 = 0.f;
#pragma unroll
    for (int i = 0; i < 2; ++i) {
      const float4 v = *(const float4*)(xf + i * 4 * T_);
      racc[i][0] += u3 * v.x; racc[i][1] += u3 * v.y;
      racc[i][2] += u3 * v.z; racc[i][3] += u3 * v.w;
      p0 += u1c[i] * v.x; p1 += u1c[i] * v.y;
      p2 += u1c[i] * v.z; p3 += u1c[i] * v.w;
    }
    // reduce over the 4 n_sub groups (lane bits 4-5)
    p0 += __shfl_xor(p0, 16); p0 += __shfl_xor(p0, 32);
    p1 += __shfl_xor(p1, 16); p1 += __shfl_xor(p1, 32);
    p2 += __shfl_xor(p2, 16); p2 += __shfl_xor(p2, 32);
    p3 += __shfl_xor(p3, 16); p3 += __shfl_xor(p3, 32);
    if (lane < 16) {
      float4 st; st.x = p0; st.y = p1; st.z = p2; st.w = p3;
      *(float4*)&t1part[((size_t)(b * 64 + nc) * 64 + f) * 64 + t0] = st;
    }
  }

  // cross-wave reduce for rhs: lds[w][n_local*64 + t]
#pragma unroll
  for (int i = 0; i < 2; ++i) {
    float4 st; st.x = racc[i][0]; st.y = racc[i][1]; st.z = racc[i][2]; st.w = racc[i][3];
    *(float4*)&lds[w][(i * 4 + n_sub) * 64 + t0] = st;
  }
  __syncthreads();
#pragma unroll
  for (int q = 0; q < 2; ++q) {
    const int idx = q * 256 + tid;  // n_local*64 + t, 0..511
    const float s = lds[0][idx] + lds[1][idx] + lds[2][idx] + lds[3][idx];
    rhs[((size_t)b * N_ + n0 + (idx >> 6)) * T_ + (idx & 63)] = s;
  }
}

// wpart[b,c,f,s] = sum_{n in 64-chunk c} U2[n,f] * rhs[b,n,s]
__global__ __launch_bounds__(256) void k2_w(const float* __restrict__ rhs,
    const float* __restrict__ U2, float* __restrict__ wpart) {
  const int b = blockIdx.x;
  const int c = blockIdx.y;
  const int n0 = c * 64;
  const int tid = threadIdx.x;
  const int s = tid & 63;
  const int fg = tid >> 6;
  __shared__ float lu2[64 * 64];
  __shared__ float lr[64 * 64];
#pragma unroll
  for (int q = 0; q < 16; ++q) {
    const int idx = q * 256 + tid;
    const int i = idx >> 6, cc = idx & 63;
    lu2[idx] = U2[(size_t)(n0 + i) * F_ + cc];
    lr[idx] = rhs[((size_t)b * N_ + n0 + i) * T_ + cc];
  }
  __syncthreads();
  float acc[16];
#pragma unroll
  for (int j = 0; j < 16; ++j) acc[j] = 0.f;
  for (int i = 0; i < 64; ++i) {
    const float rv = lr[i * 64 + s];
#pragma unroll
    for (int j = 0; j < 16; ++j) acc[j] += lu2[i * 64 + fg * 16 + j] * rv;
  }
#pragma unroll
  for (int j = 0; j < 16; ++j)
    wpart[(size_t)(b * 8 + c) * 4096 + (size_t)(fg * 16 + j) * 64 + s] = acc[j];
}

// Collapse partials: t1[b,f,t] = sum_c(64) t1part ; wbf[b,f,s] = sum_c(8) wpart
__global__ __launch_bounds__(256) void kred(const float* __restrict__ t1part,
    const float* __restrict__ wpart, float* __restrict__ t1, float* __restrict__ wbf) {
  const int gid = blockIdx.x * 256 + threadIdx.x;
  if (gid < 131072) {
    const int b = gid >> 12, idx = gid & 4095;
    const float* p = t1part + (size_t)b * 64 * 4096 + idx;
    float sum = 0.f;
#pragma unroll
    for (int c = 0; c < 64; ++c) sum += p[c * 4096];
    t1[gid] = sum;
  } else {
    const int g = gid - 131072;
    const int b = g >> 12, idx = g & 4095;
    const float* p = wpart + (size_t)b * 8 * 4096 + idx;
    float sum = 0.f;
#pragma unroll
    for (int c = 0; c < 8; ++c) sum += p[c * 4096];
    wbf[g] = sum;
  }
}

// Per-batch: product = t1^T w; S = sigmoid(product+be); E = Ve*S; A = softmax_t(E)
__global__ __launch_bounds__(256) void k3_attn(const float* __restrict__ t1,
    const float* __restrict__ wbuf, const float* __restrict__ be,
    const float* __restrict__ Ve, float* __restrict__ Amat) {
  const int b = blockIdx.x;
  const int tid = threadIdx.x;
  const int lane = tid & 63;
  const int tg = tid >> 6;
  __shared__ float bufA[64 * 65];
  __shared__ float bufB[64 * 65];
  __shared__ float red[2][4][64];
#pragma unroll
  for (int q = 0; q < 16; ++q) {
    const int idx = q * 256 + tid;
    const int r = idx >> 6, c = idx & 63;
    bufA[r * 65 + c] = t1[(size_t)b * 4096 + idx];   // [f][t]
    bufB[r * 65 + c] = wbuf[(size_t)b * 4096 + idx]; // [f][s]
  }
  __syncthreads();
  float prod[16];
#pragma unroll
  for (int j = 0; j < 16; ++j) prod[j] = 0.f;
  for (int f = 0; f < 64; ++f) {
    const float wv = bufB[f * 65 + lane];
#pragma unroll
    for (int j = 0; j < 16; ++j) prod[j] += bufA[f * 65 + tg * 16 + j] * wv;
  }
  __syncthreads();
#pragma unroll
  for (int j = 0; j < 16; ++j) {
    const int tt = tg * 16 + j;
    const float v = prod[j] + be[tt * 64 + lane];
    bufA[tt * 65 + lane] = 1.f / (1.f + __expf(-v));
  }
#pragma unroll
  for (int q = 0; q < 16; ++q) {
    const int idx = q * 256 + tid;
    bufB[(idx >> 6) * 65 + (idx & 63)] = Ve[idx];
  }
  __syncthreads();
  float E[16];
#pragma unroll
  for (int j = 0; j < 16; ++j) E[j] = 0.f;
  for (int s = 0; s < 64; ++s) {
    const float sv = bufA[s * 65 + lane];
#pragma unroll
    for (int j = 0; j < 16; ++j) E[j] += bufB[(tg * 16 + j) * 65 + s] * sv;
  }
  float m = E[0];
#pragma unroll
  for (int j = 1; j < 16; ++j) m = fmaxf(m, E[j]);
  red[0][tg][lane] = m;
  __syncthreads();
  m = fmaxf(fmaxf(red[0][0][lane], red[0][1][lane]),
            fmaxf(red[0][2][lane], red[0][3][lane]));
  float se = 0.f;
  float ex[16];
#pragma unroll
  for (int j = 0; j < 16; ++j) { ex[j] = __expf(E[j] - m); se += ex[j]; }
  red[1][tg][lane] = se;
  __syncthreads();
  const float gs = red[1][0][lane] + red[1][1][lane] + red[1][2][lane] + red[1][3][lane];
  const float inv = 1.f / gs;
#pragma unroll
  for (int j = 0; j < 16; ++j) {
    const int tt = tg * 16 + j;
    Amat[(size_t)b * 4096 + tt * 64 + lane] = ex[j] * inv;
  }
}

// out[b,fn,s] = sum_t x[b,fn,t] * A[b,t,s] via bf16 MFMA. Wave = 16 rows x 64 cols.
__global__ __launch_bounds__(256) void k4_out(const float* __restrict__ x,
    const float* __restrict__ Amat, float* __restrict__ out) {
  const int b = blockIdx.x;
  const int chunk = blockIdx.y;
  const int tid = threadIdx.x;
  const int wv = tid >> 6;
  const int l = tid & 63;
  __shared__ float lA[64 * 65];
  const float* Ab = Amat + (size_t)b * 4096;
#pragma unroll
  for (int q = 0; q < 16; ++q) {
    const int idx = q * 256 + tid;
    lA[(idx >> 6) * 65 + (idx & 63)] = Ab[idx];
  }
  __syncthreads();

  const int krow0 = (l >> 4) * 8;
  const int colb = l & 15;
  bf16x8 Bf[4][2];
#pragma unroll
  for (int nt = 0; nt < 4; ++nt)
#pragma unroll
    for (int kh = 0; kh < 2; ++kh) {
      bf16x8 fr;
#pragma unroll
      for (int j = 0; j < 8; ++j) {
        const int k = kh * 32 + krow0 + j;
        fr[j] = (short)f2bf(lA[k * 65 + nt * 16 + colb]);
      }
      Bf[nt][kh] = fr;
    }

  const float* Xb = x + (size_t)b * (F_ * (size_t)N_ * T_);
  float* Ob = out + (size_t)b * (F_ * (size_t)N_ * T_);
  const int rl = l & 15;
  const int c0 = (l >> 4) * 8;

  for (int it = 0; it < 4; ++it) {
    const int tile = chunk * 16 + wv * 4 + it;  // 0..2047
    const int r = tile * 16 + rl;
    const float* xr = Xb + (size_t)r * T_;
    const float4 v0 = *(const float4*)(xr + c0);
    const float4 v1 = *(const float4*)(xr + c0 + 4);
    const float4 v2 = *(const float4*)(xr + 32 + c0);
    const float4 v3 = *(const float4*)(xr + 32 + c0 + 4);
    bf16x8 a0, a1;
    a0[0] = (short)f2bf(v0.x); a0[1] = (short)f2bf(v0.y);
    a0[2] = (short)f2bf(v0.z); a0[3] = (short)f2bf(v0.w);
    a0[4] = (short)f2bf(v1.x); a0[5] = (short)f2bf(v1.y);
    a0[6] = (short)f2bf(v1.z); a0[7] = (short)f2bf(v1.w);
    a1[0] = (short)f2bf(v2.x); a1[1] = (short)f2bf(v2.y);
    a1[2] = (short)f2bf(v2.z); a1[3] = (short)f2bf(v2.w);
    a1[4] = (short)f2bf(v3.x); a1[5] = (short)f2bf(v3.y);
    a1[6] = (short)f2bf(v3.z); a1[7] = (short)f2bf(v3.w);

    const int rowb = tile * 16 + (l >> 4) * 4;
#pragma unroll
    for (int nt = 0; nt < 4; ++nt) {
      f32x4 c = {0.f, 0.f, 0.f, 0.f};
      c = __builtin_amdgcn_mfma_f32_16x16x32_bf16(a0, Bf[nt][0], c, 0, 0, 0);
      c = __builtin_amdgcn_mfma_f32_16x16x32_bf16(a1, Bf[nt][1], c, 0, 0, 0);
#pragma unroll
      for (int j = 0; j < 4; ++j)
        Ob[(size_t)(rowb + j) * T_ + nt * 16 + colb] = c[j];
    }
  }
}

extern "C" void kernel_launch(void* const* d_in, const int* in_sizes, int n_in,
                              void* d_out, int out_size, void* d_ws, size_t ws_size,
                              hipStream_t stream) {
  const float* x  = (const float*)d_in[0];
  const float* U1 = (const float*)d_in[1];
  const float* U2 = (const float*)d_in[2];
  const float* U3 = (const float*)d_in[3];
  const float* be = (const float*)d_in[4];
  const float* Ve = (const float*)d_in[5];
  float* out = (float*)d_out;
  float* ws = (float*)d_ws;

  float* t1part = ws;                    // 32*64*4096 = 8,388,608 floats (32 MB)
  float* rhs    = t1part + 8388608;      // 32*512*64  = 1,048,576 floats (4 MB)
  float* wpart  = rhs + 1048576;         // 32*8*4096  = 1,048,576 floats (4 MB)
  float* t1     = wpart + 1048576;       // 131072 floats
  float* wbf    = t1 + 131072;           // 131072 floats
  float* Amat   = wbf + 131072;          // 131072 floats

  k1_reduce<<<dim3(32, 64), 256, 0, stream>>>(x, U1, U3, t1part, rhs);
  k2_w<<<dim3(32, 8), 256, 0, stream>>>(rhs, U2, wpart);
  kred<<<1024, 256, 0, stream>>>(t1part, wpart, t1, wbf);
  k3_attn<<<32, 256, 0, stream>>>(t1, wbf, be, Ve, Amat);
  k4_out<<<dim3(32, 128), 256, 0, stream>>>(x, Amat, out);
}

// Round 8
// 271.931 us; speedup vs baseline: 1.2378x; 1.2378x over previous
//
#include <hip/hip_runtime.h>
#include <hip/hip_bf16.h>

#define B_ 32
#define F_ 64
#define N_ 512
#define T_ 64

typedef __attribute__((ext_vector_type(8))) short bf16x8;
typedef __attribute__((ext_vector_type(4))) float f32x4;

__device__ __forceinline__ unsigned short f2bf(float f) {
  union { float f; unsigned int u; } v; v.f = f;
  unsigned int u = v.u;
  unsigned int r = (u + 0x7FFFu + ((u >> 16) & 1u)) >> 16;
  return (unsigned short)r;
}

// Pass 1 over x. Block=(b, f-group of 8) -> 256 blocks x 1024 threads.
// Each block streams x[b, fg*8 .. fg*8+8, :, :] = 1 MB FULLY SEQUENTIAL.
// Per f-slab (128 KB): 1024 threads x 8 float4 sweeps (16 KB per sweep).
// Thread tid holds rows {i*64 + (tid>>4)}, t-slice (tid&15)*4.
//   t1[b,f,t]            exact (shuffle + end-of-kernel LDS reduce, no per-f barrier)
//   rhs_part[b,fg,n*64+t] = sum_{f in group} U3[f]*x  (coalesced float4 stores)
__global__ __launch_bounds__(1024) void k1_reduce(const float* __restrict__ x,
    const float* __restrict__ U1, const float* __restrict__ U3,
    float* __restrict__ t1, float* __restrict__ rhs_part) {
  const int b = blockIdx.x;
  const int fg = blockIdx.y;
  const int tid = threadIdx.x;
  const int w = tid >> 6;
  const int lane = tid & 63;
  const int r4 = tid >> 4;  // row subgroup 0..63

  __shared__ float ts1[8][16][16][4];  // [f-local][wave][t-slice][k] = 32 KB

  const float* slab0 = x + (size_t)(b * 64 + fg * 8) * 32768;

  float u1c[8];
#pragma unroll
  for (int i = 0; i < 8; ++i) u1c[i] = U1[i * 64 + r4];

  float racc[8][4];
#pragma unroll
  for (int i = 0; i < 8; ++i)
#pragma unroll
    for (int k = 0; k < 4; ++k) racc[i][k] = 0.f;

#pragma unroll
  for (int j = 0; j < 8; ++j) {
    const int f = fg * 8 + j;
    const float u3 = U3[f];
    const float* fs = slab0 + (size_t)j * 32768 + tid * 4;
    float4 buf[8];
#pragma unroll
    for (int i = 0; i < 8; ++i) buf[i] = *(const float4*)(fs + i * 4096);
    float p0 = 0.f, p1 = 0.f, p2 = 0.f, p3 = 0.f;
#pragma unroll
    for (int i = 0; i < 8; ++i) {
      const float4 v = buf[i];
      racc[i][0] += u3 * v.x; racc[i][1] += u3 * v.y;
      racc[i][2] += u3 * v.z; racc[i][3] += u3 * v.w;
      p0 += u1c[i] * v.x; p1 += u1c[i] * v.y;
      p2 += u1c[i] * v.z; p3 += u1c[i] * v.w;
    }
    // combine the 4 row-subgroups within the wave (lane bits 4-5)
    p0 += __shfl_xor(p0, 16); p0 += __shfl_xor(p0, 32);
    p1 += __shfl_xor(p1, 16); p1 += __shfl_xor(p1, 32);
    p2 += __shfl_xor(p2, 16); p2 += __shfl_xor(p2, 32);
    p3 += __shfl_xor(p3, 16); p3 += __shfl_xor(p3, 32);
    if (lane < 16) {
      ts1[j][w][lane][0] = p0; ts1[j][w][lane][1] = p1;
      ts1[j][w][lane][2] = p2; ts1[j][w][lane][3] = p3;
    }
  }

  // rhs partial: coalesced float4 stores (same flat positions for all f)
  float* rp = rhs_part + (size_t)(b * 8 + fg) * 32768 + tid * 4;
#pragma unroll
  for (int i = 0; i < 8; ++i) {
    float4 st; st.x = racc[i][0]; st.y = racc[i][1];
    st.z = racc[i][2]; st.w = racc[i][3];
    *(float4*)(rp + i * 4096) = st;
  }

  // single end-of-kernel t1 reduce across the 16 waves
  __syncthreads();
  if (tid < 512) {
    const int j = tid >> 6;       // f-local
    const int t = tid & 63;
    float s = 0.f;
#pragma unroll
    for (int ww = 0; ww < 16; ++ww) s += ts1[j][ww][t >> 2][t & 3];
    t1[(size_t)b * 4096 + (fg * 8 + j) * 64 + t] = s;
  }
}

// wpart[b,c,f,s] = sum_{n in 64-chunk c} U2[n,f] * rhs[b,n,s],
// with rhs folded on load: rhs[b,n,s] = sum_fg rhs_part[b,fg,n*64+s]
__global__ __launch_bounds__(256) void k2_w(const float* __restrict__ rhs_part,
    const float* __restrict__ U2, float* __restrict__ wpart) {
  const int b = blockIdx.x;
  const int c = blockIdx.y;
  const int n0 = c * 64;
  const int tid = threadIdx.x;
  const int s = tid & 63;
  const int fg = tid >> 6;
  __shared__ float lu2[64 * 64];
  __shared__ float lr[64 * 64];
#pragma unroll
  for (int q = 0; q < 16; ++q) {
    const int idx = q * 256 + tid;
    const int i = idx >> 6, cc = idx & 63;
    lu2[idx] = U2[(size_t)(n0 + i) * F_ + cc];
    const float* p = rhs_part + (size_t)b * 8 * 32768 + (size_t)n0 * 64 + idx;
    float sum = 0.f;
#pragma unroll
    for (int g = 0; g < 8; ++g) sum += p[(size_t)g * 32768];
    lr[idx] = sum;
  }
  __syncthreads();
  float acc[16];
#pragma unroll
  for (int j = 0; j < 16; ++j) acc[j] = 0.f;
  for (int i = 0; i < 64; ++i) {
    const float rv = lr[i * 64 + s];
#pragma unroll
    for (int j = 0; j < 16; ++j) acc[j] += lu2[i * 64 + fg * 16 + j] * rv;
  }
#pragma unroll
  for (int j = 0; j < 16; ++j)
    wpart[(size_t)(b * 8 + c) * 4096 + (size_t)(fg * 16 + j) * 64 + s] = acc[j];
}

// Per-batch: product = t1^T w; S = sigmoid(product+be); E = Ve*S; A = softmax_t(E)
// w folded on load from wpart (8-way sum).
__global__ __launch_bounds__(256) void k3_attn(const float* __restrict__ t1,
    const float* __restrict__ wpart, const float* __restrict__ be,
    const float* __restrict__ Ve, float* __restrict__ Amat) {
  const int b = blockIdx.x;
  const int tid = threadIdx.x;
  const int lane = tid & 63;
  const int tg = tid >> 6;
  __shared__ float bufA[64 * 65];
  __shared__ float bufB[64 * 65];
  __shared__ float red[2][4][64];
#pragma unroll
  for (int q = 0; q < 16; ++q) {
    const int idx = q * 256 + tid;
    const int r = idx >> 6, c = idx & 63;
    bufA[r * 65 + c] = t1[(size_t)b * 4096 + idx];   // [f][t]
    const float* p = wpart + (size_t)b * 8 * 4096 + idx;
    float sum = 0.f;
#pragma unroll
    for (int g = 0; g < 8; ++g) sum += p[(size_t)g * 4096];
    bufB[r * 65 + c] = sum;                           // [f][s]
  }
  __syncthreads();
  float prod[16];
#pragma unroll
  for (int j = 0; j < 16; ++j) prod[j] = 0.f;
  for (int f = 0; f < 64; ++f) {
    const float wv = bufB[f * 65 + lane];
#pragma unroll
    for (int j = 0; j < 16; ++j) prod[j] += bufA[f * 65 + tg * 16 + j] * wv;
  }
  __syncthreads();
#pragma unroll
  for (int j = 0; j < 16; ++j) {
    const int tt = tg * 16 + j;
    const float v = prod[j] + be[tt * 64 + lane];
    bufA[tt * 65 + lane] = 1.f / (1.f + __expf(-v));
  }
#pragma unroll
  for (int q = 0; q < 16; ++q) {
    const int idx = q * 256 + tid;
    bufB[(idx >> 6) * 65 + (idx & 63)] = Ve[idx];
  }
  __syncthreads();
  float E[16];
#pragma unroll
  for (int j = 0; j < 16; ++j) E[j] = 0.f;
  for (int s = 0; s < 64; ++s) {
    const float sv = bufA[s * 65 + lane];
#pragma unroll
    for (int j = 0; j < 16; ++j) E[j] += bufB[(tg * 16 + j) * 65 + s] * sv;
  }
  float m = E[0];
#pragma unroll
  for (int j = 1; j < 16; ++j) m = fmaxf(m, E[j]);
  red[0][tg][lane] = m;
  __syncthreads();
  m = fmaxf(fmaxf(red[0][0][lane], red[0][1][lane]),
            fmaxf(red[0][2][lane], red[0][3][lane]));
  float se = 0.f;
  float ex[16];
#pragma unroll
  for (int j = 0; j < 16; ++j) { ex[j] = __expf(E[j] - m); se += ex[j]; }
  red[1][tg][lane] = se;
  __syncthreads();
  const float gs = red[1][0][lane] + red[1][1][lane] + red[1][2][lane] + red[1][3][lane];
  const float inv = 1.f / gs;
#pragma unroll
  for (int j = 0; j < 16; ++j) {
    const int tt = tg * 16 + j;
    Amat[(size_t)b * 4096 + tt * 64 + lane] = ex[j] * inv;
  }
}

// out[b,fn,s] = sum_t x[b,fn,t] * A[b,t,s] via bf16 MFMA. Wave = 16 rows x 64 cols.
__global__ __launch_bounds__(256) void k4_out(const float* __restrict__ x,
    const float* __restrict__ Amat, float* __restrict__ out) {
  const int b = blockIdx.x;
  const int chunk = blockIdx.y;
  const int tid = threadIdx.x;
  const int wv = tid >> 6;
  const int l = tid & 63;
  __shared__ float lA[64 * 65];
  const float* Ab = Amat + (size_t)b * 4096;
#pragma unroll
  for (int q = 0; q < 16; ++q) {
    const int idx = q * 256 + tid;
    lA[(idx >> 6) * 65 + (idx & 63)] = Ab[idx];
  }
  __syncthreads();

  const int krow0 = (l >> 4) * 8;
  const int colb = l & 15;
  bf16x8 Bf[4][2];
#pragma unroll
  for (int nt = 0; nt < 4; ++nt)
#pragma unroll
    for (int kh = 0; kh < 2; ++kh) {
      bf16x8 fr;
#pragma unroll
      for (int j = 0; j < 8; ++j) {
        const int k = kh * 32 + krow0 + j;
        fr[j] = (short)f2bf(lA[k * 65 + nt * 16 + colb]);
      }
      Bf[nt][kh] = fr;
    }

  const float* Xb = x + (size_t)b * (F_ * (size_t)N_ * T_);
  float* Ob = out + (size_t)b * (F_ * (size_t)N_ * T_);
  const int rl = l & 15;
  const int c0 = (l >> 4) * 8;

  for (int it = 0; it < 4; ++it) {
    const int tile = chunk * 16 + wv * 4 + it;  // 0..2047
    const int r = tile * 16 + rl;
    const float* xr = Xb + (size_t)r * T_;
    const float4 v0 = *(const float4*)(xr + c0);
    const float4 v1 = *(const float4*)(xr + c0 + 4);
    const float4 v2 = *(const float4*)(xr + 32 + c0);
    const float4 v3 = *(const float4*)(xr + 32 + c0 + 4);
    bf16x8 a0, a1;
    a0[0] = (short)f2bf(v0.x); a0[1] = (short)f2bf(v0.y);
    a0[2] = (short)f2bf(v0.z); a0[3] = (short)f2bf(v0.w);
    a0[4] = (short)f2bf(v1.x); a0[5] = (short)f2bf(v1.y);
    a0[6] = (short)f2bf(v1.z); a0[7] = (short)f2bf(v1.w);
    a1[0] = (short)f2bf(v2.x); a1[1] = (short)f2bf(v2.y);
    a1[2] = (short)f2bf(v2.z); a1[3] = (short)f2bf(v2.w);
    a1[4] = (short)f2bf(v3.x); a1[5] = (short)f2bf(v3.y);
    a1[6] = (short)f2bf(v3.z); a1[7] = (short)f2bf(v3.w);

    const int rowb = tile * 16 + (l >> 4) * 4;
#pragma unroll
    for (int nt = 0; nt < 4; ++nt) {
      f32x4 c = {0.f, 0.f, 0.f, 0.f};
      c = __builtin_amdgcn_mfma_f32_16x16x32_bf16(a0, Bf[nt][0], c, 0, 0, 0);
      c = __builtin_amdgcn_mfma_f32_16x16x32_bf16(a1, Bf[nt][1], c, 0, 0, 0);
#pragma unroll
      for (int j = 0; j < 4; ++j)
        Ob[(size_t)(rowb + j) * T_ + nt * 16 + colb] = c[j];
    }
  }
}

extern "C" void kernel_launch(void* const* d_in, const int* in_sizes, int n_in,
                              void* d_out, int out_size, void* d_ws, size_t ws_size,
                              hipStream_t stream) {
  const float* x  = (const float*)d_in[0];
  const float* U1 = (const float*)d_in[1];
  const float* U2 = (const float*)d_in[2];
  const float* U3 = (const float*)d_in[3];
  const float* be = (const float*)d_in[4];
  const float* Ve = (const float*)d_in[5];
  float* out = (float*)d_out;
  float* ws = (float*)d_ws;

  float* rhs_part = ws;                    // 32*8*32768 = 8,388,608 floats (32 MB)
  float* wpart    = rhs_part + 8388608;    // 32*8*4096  = 1,048,576 floats (4 MB)
  float* t1       = wpart + 1048576;       // 131072 floats
  float* Amat     = t1 + 131072;           // 131072 floats

  k1_reduce<<<dim3(32, 8), 1024, 0, stream>>>(x, U1, U3, t1, rhs_part);
  k2_w<<<dim3(32, 8), 256, 0, stream>>>(rhs_part, U2, wpart);
  k3_attn<<<32, 256, 0, stream>>>(t1, wpart, be, Ve, Amat);
  k4_out<<<dim3(32, 128), 256, 0, stream>>>(x, Amat, out);
}

// Round 9
// 242.081 us; speedup vs baseline: 1.3905x; 1.1233x over previous
//
#include <hip/hip_runtime.h>
#include <hip/hip_bf16.h>

#define B_ 32
#define F_ 64
#define N_ 512
#define T_ 64

typedef __attribute__((ext_vector_type(8))) short bf16x8;
typedef __attribute__((ext_vector_type(4))) float f32x4;

__device__ __forceinline__ unsigned short f2bf(float f) {
  union { float f; unsigned int u; } v; v.f = f;
  unsigned int u = v.u;
  unsigned int r = (u + 0x7FFFu + ((u >> 16) & 1u)) >> 16;
  return (unsigned short)r;
}

// Pass 1 over x. Block=(b, 16-n chunk), 1024 blocks x 256 thr (16 waves/CU).
// Wave w owns f in [16w,16w+16). Lane: n_sub=lane>>4, t0=(lane&15)*4.
// HOT LOOP IS CROSS-LANE-FREE: per f = 4 float4 loads + 32 FMA + one fully
// coalesced 1KB store of per-lane t1 partials. No shfl, no branch, no LDS.
//   t1part[b,nc,f,nsub*64+t] = sum_{i} U1[n]*x   (folded 128-way in kred)
//   rhs[b,n,t] = sum_f U3[f]*x                    (cross-wave LDS fold, tail only)
__global__ __launch_bounds__(256) void k1_reduce(const float* __restrict__ x,
    const float* __restrict__ U1, const float* __restrict__ U3,
    float* __restrict__ t1part, float* __restrict__ rhs) {
  const int b = blockIdx.x;
  const int nc = blockIdx.y;
  const int n0 = nc * 16;
  const int tid = threadIdx.x;
  const int w = tid >> 6;
  const int lane = tid & 63;
  const int n_sub = lane >> 4;
  const int t0 = (lane & 15) * 4;

  __shared__ float lds[4][1024];

  const float* xb = x + (size_t)b * (F_ * (size_t)N_ * T_);

  float u1c[4];
#pragma unroll
  for (int i = 0; i < 4; ++i) u1c[i] = U1[n0 + n_sub * 4 + i];

  float racc[4][4];
#pragma unroll
  for (int i = 0; i < 4; ++i)
#pragma unroll
    for (int k = 0; k < 4; ++k) racc[i][k] = 0.f;

  // t1part base for this (b,nc): one 1KB run per f, lane*4 within it
  float* tp = t1part + ((size_t)(b * 32 + nc) * 64) * 256 + lane * 4;

#pragma unroll
  for (int j = 0; j < 16; ++j) {
    const int f = w * 16 + j;
    const float u3 = U3[f];
    const float* xf = xb + (size_t)f * (N_ * T_) + (size_t)(n0 + n_sub * 4) * T_ + t0;
    float4 buf[4];
#pragma unroll
    for (int i = 0; i < 4; ++i) buf[i] = *(const float4*)(xf + i * T_);
    float p0 = 0.f, p1 = 0.f, p2 = 0.f, p3 = 0.f;
#pragma unroll
    for (int i = 0; i < 4; ++i) {
      const float4 v = buf[i];
      racc[i][0] += u3 * v.x; racc[i][1] += u3 * v.y;
      racc[i][2] += u3 * v.z; racc[i][3] += u3 * v.w;
      p0 += u1c[i] * v.x; p1 += u1c[i] * v.y;
      p2 += u1c[i] * v.z; p3 += u1c[i] * v.w;
    }
    float4 st; st.x = p0; st.y = p1; st.z = p2; st.w = p3;
    *(float4*)(tp + (size_t)f * 256) = st;
  }

  // cross-wave reduce for rhs (off the hot path)
#pragma unroll
  for (int i = 0; i < 4; ++i) {
    float4 st; st.x = racc[i][0]; st.y = racc[i][1]; st.z = racc[i][2]; st.w = racc[i][3];
    *(float4*)&lds[w][(n_sub * 4 + i) * 64 + t0] = st;
  }
  __syncthreads();
#pragma unroll
  for (int q = 0; q < 4; ++q) {
    const int idx = q * 256 + tid;  // n_local*64 + t
    const float s = lds[0][idx] + lds[1][idx] + lds[2][idx] + lds[3][idx];
    rhs[((size_t)b * N_ + n0 + (idx >> 6)) * T_ + (idx & 63)] = s;
  }
}

// wpart[b,c,f,s] = sum_{n in 64-chunk c} U2[n,f] * rhs[b,n,s]
__global__ __launch_bounds__(256) void k2_w(const float* __restrict__ rhs,
    const float* __restrict__ U2, float* __restrict__ wpart) {
  const int b = blockIdx.x;
  const int c = blockIdx.y;
  const int n0 = c * 64;
  const int tid = threadIdx.x;
  const int s = tid & 63;
  const int fg = tid >> 6;
  __shared__ float lu2[64 * 64];
  __shared__ float lr[64 * 64];
#pragma unroll
  for (int q = 0; q < 16; ++q) {
    const int idx = q * 256 + tid;
    const int i = idx >> 6, cc = idx & 63;
    lu2[idx] = U2[(size_t)(n0 + i) * F_ + cc];
    lr[idx] = rhs[((size_t)b * N_ + n0 + i) * T_ + cc];
  }
  __syncthreads();
  float acc[16];
#pragma unroll
  for (int j = 0; j < 16; ++j) acc[j] = 0.f;
  for (int i = 0; i < 64; ++i) {
    const float rv = lr[i * 64 + s];
#pragma unroll
    for (int j = 0; j < 16; ++j) acc[j] += lu2[i * 64 + fg * 16 + j] * rv;
  }
#pragma unroll
  for (int j = 0; j < 16; ++j)
    wpart[(size_t)(b * 8 + c) * 4096 + (size_t)(fg * 16 + j) * 64 + s] = acc[j];
}

// t1[b,f,t] = sum over nc(32) x nsub(4) of t1part ; wbf = 8-way wpart fold
__global__ __launch_bounds__(256) void kred(const float* __restrict__ t1part,
    const float* __restrict__ wpart, float* __restrict__ t1, float* __restrict__ wbf) {
  const int gid = blockIdx.x * 256 + threadIdx.x;
  if (gid < 131072) {
    const int b = gid >> 12;
    const int f = (gid >> 6) & 63;
    const int t = gid & 63;
    const float* p = t1part + ((size_t)(b * 32) * 64 + f) * 256 + t;
    float sum = 0.f;
#pragma unroll 4
    for (int nc = 0; nc < 32; ++nc) {
      const float* q = p + (size_t)nc * (64 * 256);
      sum += q[0] + q[64] + q[128] + q[192];
    }
    t1[gid] = sum;
  } else {
    const int g = gid - 131072;
    const int b = g >> 12, idx = g & 4095;
    const float* p = wpart + (size_t)b * 8 * 4096 + idx;
    float sum = 0.f;
#pragma unroll
    for (int c = 0; c < 8; ++c) sum += p[c * 4096];
    wbf[g] = sum;
  }
}

// Per-batch: product = t1^T w; S = sigmoid(product+be); E = Ve*S; A = softmax_t(E)
__global__ __launch_bounds__(256) void k3_attn(const float* __restrict__ t1,
    const float* __restrict__ wbuf, const float* __restrict__ be,
    const float* __restrict__ Ve, float* __restrict__ Amat) {
  const int b = blockIdx.x;
  const int tid = threadIdx.x;
  const int lane = tid & 63;
  const int tg = tid >> 6;
  __shared__ float bufA[64 * 65];
  __shared__ float bufB[64 * 65];
  __shared__ float red[2][4][64];
#pragma unroll
  for (int q = 0; q < 16; ++q) {
    const int idx = q * 256 + tid;
    const int r = idx >> 6, c = idx & 63;
    bufA[r * 65 + c] = t1[(size_t)b * 4096 + idx];   // [f][t]
    bufB[r * 65 + c] = wbuf[(size_t)b * 4096 + idx]; // [f][s]
  }
  __syncthreads();
  float prod[16];
#pragma unroll
  for (int j = 0; j < 16; ++j) prod[j] = 0.f;
  for (int f = 0; f < 64; ++f) {
    const float wv = bufB[f * 65 + lane];
#pragma unroll
    for (int j = 0; j < 16; ++j) prod[j] += bufA[f * 65 + tg * 16 + j] * wv;
  }
  __syncthreads();
#pragma unroll
  for (int j = 0; j < 16; ++j) {
    const int tt = tg * 16 + j;
    const float v = prod[j] + be[tt * 64 + lane];
    bufA[tt * 65 + lane] = 1.f / (1.f + __expf(-v));
  }
#pragma unroll
  for (int q = 0; q < 16; ++q) {
    const int idx = q * 256 + tid;
    bufB[(idx >> 6) * 65 + (idx & 63)] = Ve[idx];
  }
  __syncthreads();
  float E[16];
#pragma unroll
  for (int j = 0; j < 16; ++j) E[j] = 0.f;
  for (int s = 0; s < 64; ++s) {
    const float sv = bufA[s * 65 + lane];
#pragma unroll
    for (int j = 0; j < 16; ++j) E[j] += bufB[(tg * 16 + j) * 65 + s] * sv;
  }
  float m = E[0];
#pragma unroll
  for (int j = 1; j < 16; ++j) m = fmaxf(m, E[j]);
  red[0][tg][lane] = m;
  __syncthreads();
  m = fmaxf(fmaxf(red[0][0][lane], red[0][1][lane]),
            fmaxf(red[0][2][lane], red[0][3][lane]));
  float se = 0.f;
  float ex[16];
#pragma unroll
  for (int j = 0; j < 16; ++j) { ex[j] = __expf(E[j] - m); se += ex[j]; }
  red[1][tg][lane] = se;
  __syncthreads();
  const float gs = red[1][0][lane] + red[1][1][lane] + red[1][2][lane] + red[1][3][lane];
  const float inv = 1.f / gs;
#pragma unroll
  for (int j = 0; j < 16; ++j) {
    const int tt = tg * 16 + j;
    Amat[(size_t)b * 4096 + tt * 64 + lane] = ex[j] * inv;
  }
}

// out[b,fn,s] = sum_t x[b,fn,t] * A[b,t,s] via bf16 MFMA. Wave = 16 rows x 64 cols.
// b0: batch offset (launched in 4 reverse-ordered groups for L3 reuse of x).
__global__ __launch_bounds__(256) void k4_out(const float* __restrict__ x,
    const float* __restrict__ Amat, float* __restrict__ out, int b0) {
  const int b = b0 + blockIdx.x;
  const int chunk = blockIdx.y;
  const int tid = threadIdx.x;
  const int wv = tid >> 6;
  const int l = tid & 63;
  __shared__ float lA[64 * 65];
  const float* Ab = Amat + (size_t)b * 4096;
#pragma unroll
  for (int q = 0; q < 16; ++q) {
    const int idx = q * 256 + tid;
    lA[(idx >> 6) * 65 + (idx & 63)] = Ab[idx];
  }
  __syncthreads();

  const int krow0 = (l >> 4) * 8;
  const int colb = l & 15;
  bf16x8 Bf[4][2];
#pragma unroll
  for (int nt = 0; nt < 4; ++nt)
#pragma unroll
    for (int kh = 0; kh < 2; ++kh) {
      bf16x8 fr;
#pragma unroll
      for (int j = 0; j < 8; ++j) {
        const int k = kh * 32 + krow0 + j;
        fr[j] = (short)f2bf(lA[k * 65 + nt * 16 + colb]);
      }
      Bf[nt][kh] = fr;
    }

  const float* Xb = x + (size_t)b * (F_ * (size_t)N_ * T_);
  float* Ob = out + (size_t)b * (F_ * (size_t)N_ * T_);
  const int rl = l & 15;
  const int c0 = (l >> 4) * 8;

  for (int it = 0; it < 4; ++it) {
    const int tile = chunk * 16 + wv * 4 + it;  // 0..2047
    const int r = tile * 16 + rl;
    const float* xr = Xb + (size_t)r * T_;
    const float4 v0 = *(const float4*)(xr + c0);
    const float4 v1 = *(const float4*)(xr + c0 + 4);
    const float4 v2 = *(const float4*)(xr + 32 + c0);
    const float4 v3 = *(const float4*)(xr + 32 + c0 + 4);
    bf16x8 a0, a1;
    a0[0] = (short)f2bf(v0.x); a0[1] = (short)f2bf(v0.y);
    a0[2] = (short)f2bf(v0.z); a0[3] = (short)f2bf(v0.w);
    a0[4] = (short)f2bf(v1.x); a0[5] = (short)f2bf(v1.y);
    a0[6] = (short)f2bf(v1.z); a0[7] = (short)f2bf(v1.w);
    a1[0] = (short)f2bf(v2.x); a1[1] = (short)f2bf(v2.y);
    a1[2] = (short)f2bf(v2.z); a1[3] = (short)f2bf(v2.w);
    a1[4] = (short)f2bf(v3.x); a1[5] = (short)f2bf(v3.y);
    a1[6] = (short)f2bf(v3.z); a1[7] = (short)f2bf(v3.w);

    const int rowb = tile * 16 + (l >> 4) * 4;
#pragma unroll
    for (int nt = 0; nt < 4; ++nt) {
      f32x4 c = {0.f, 0.f, 0.f, 0.f};
      c = __builtin_amdgcn_mfma_f32_16x16x32_bf16(a0, Bf[nt][0], c, 0, 0, 0);
      c = __builtin_amdgcn_mfma_f32_16x16x32_bf16(a1, Bf[nt][1], c, 0, 0, 0);
#pragma unroll
      for (int j = 0; j < 4; ++j)
        Ob[(size_t)(rowb + j) * T_ + nt * 16 + colb] = c[j];
    }
  }
}

extern "C" void kernel_launch(void* const* d_in, const int* in_sizes, int n_in,
                              void* d_out, int out_size, void* d_ws, size_t ws_size,
                              hipStream_t stream) {
  const float* x  = (const float*)d_in[0];
  const float* U1 = (const float*)d_in[1];
  const float* U2 = (const float*)d_in[2];
  const float* U3 = (const float*)d_in[3];
  const float* be = (const float*)d_in[4];
  const float* Ve = (const float*)d_in[5];
  float* out = (float*)d_out;
  float* ws = (float*)d_ws;

  float* t1part = ws;                    // 32*32*64*256 = 16,777,216 floats (64 MB)
  float* rhs    = t1part + 16777216;     // 1,048,576 floats (4 MB)
  float* wpart  = rhs + 1048576;         // 1,048,576 floats (4 MB)
  float* t1     = wpart + 1048576;       // 131072 floats
  float* wbf    = t1 + 131072;           // 131072 floats
  float* Amat   = wbf + 131072;          // 131072 floats

  k1_reduce<<<dim3(32, 32), 256, 0, stream>>>(x, U1, U3, t1part, rhs);
  k2_w<<<dim3(32, 8), 256, 0, stream>>>(rhs, U2, wpart);
  kred<<<1024, 256, 0, stream>>>(t1part, wpart, t1, wbf);
  k3_attn<<<32, 256, 0, stream>>>(t1, wbf, be, Ve, Amat);
  // k4 in reverse batch-group order: the tail of x (read last by k1) is still
  // L3-resident, so the first k4 groups read from L3 instead of HBM.
  k4_out<<<dim3(8, 128), 256, 0, stream>>>(x, Amat, out, 24);
  k4_out<<<dim3(8, 128), 256, 0, stream>>>(x, Amat, out, 16);
  k4_out<<<dim3(8, 128), 256, 0, stream>>>(x, Amat, out, 8);
  k4_out<<<dim3(8, 128), 256, 0, stream>>>(x, Amat, out, 0);
}

// Round 10
// 209.626 us; speedup vs baseline: 1.6058x; 1.1548x over previous
//
#include <hip/hip_runtime.h>
#include <hip/hip_bf16.h>

#define B_ 32
#define F_ 64
#define N_ 512
#define T_ 64

typedef __attribute__((ext_vector_type(8))) short bf16x8;
typedef __attribute__((ext_vector_type(4))) float f32x4;

__device__ __forceinline__ unsigned short f2bf(float f) {
  union { float f; unsigned int u; } v; v.f = f;
  unsigned int u = v.u;
  unsigned int r = (u + 0x7FFFu + ((u >> 16) & 1u)) >> 16;
  return (unsigned short)r;
}

__device__ __forceinline__ unsigned int pack2bf(float a, float b) {
  return (unsigned int)f2bf(a) | ((unsigned int)f2bf(b) << 16);
}

// Pass 1 over x. Block=(b, 16-n chunk), 1024 blocks. Wave w owns f in [16w,16w+16),
// processed as 8 groups of 2 f with ping-pong VGPR prefetch.
// Iteration order: LOAD(next group, 8 loads) -> echo-STORE(current, 8 stores) ->
// FMA(current). The cvt feeding the echo waits vmcnt(8) (next loads in flight);
// stores are never drained inside the loop (r6's entanglement fix).
//   rhs[b,n,t]       = sum_f U3[f]*x            (cross-wave LDS fold, tail)
//   t1part[b,nc,f,t] = sum_{n in chunk} U1[n]*x (shuffle partial, 32 chunks)
//   xbf[b,f,n,t]     = bf16(x)                  (pass-2 operand, halves k4 reads)
__global__ __launch_bounds__(256) void k1_reduce(const float* __restrict__ x,
    const float* __restrict__ U1, const float* __restrict__ U3,
    float* __restrict__ t1part, float* __restrict__ rhs,
    unsigned short* __restrict__ xbf) {
  const int b = blockIdx.x;
  const int nc = blockIdx.y;
  const int n0 = nc * 16;
  const int tid = threadIdx.x;
  const int w = tid >> 6;
  const int lane = tid & 63;
  const int n_sub = lane >> 4;
  const int t0 = (lane & 15) * 4;

  __shared__ float lds[4][1024];

  // wave base: x[b, w*16, n0, 0]; f-slab j at +j*32768 floats
  const float* xw = x + ((size_t)(b * F_ + w * 16) * N_ + n0) * T_;
  unsigned short* xe = xbf + ((size_t)(b * F_ + w * 16) * N_ + n0 + n_sub * 4) * T_ + t0;
  const int loff = n_sub * 256 + t0;  // (n_sub*4)*64 + t0

  float u1c[4];
#pragma unroll
  for (int i = 0; i < 4; ++i) u1c[i] = U1[n0 + n_sub * 4 + i];

  float racc[4][4];
#pragma unroll
  for (int i = 0; i < 4; ++i)
#pragma unroll
    for (int k = 0; k < 4; ++k) racc[i][k] = 0.f;

  float4 bufA[2][4], bufB[2][4];

#define K1_LOAD(buf, g)                                                        \
  _Pragma("unroll") for (int i = 0; i < 4; ++i) {                              \
    buf[0][i] = *(const float4*)(xw + (size_t)(2 * (g)) * 32768 + loff + i * 64);     \
    buf[1][i] = *(const float4*)(xw + (size_t)(2 * (g) + 1) * 32768 + loff + i * 64); \
  }

#define K1_PROC(buf, g)                                                        \
  {                                                                            \
    const int f0 = 2 * (g);                                                    \
    /* echo stores first: waits only for THIS buf's loads (vmcnt leaves the */ \
    /* just-issued next-group loads outstanding), FMAs below need no wait.  */ \
    _Pragma("unroll") for (int fb = 0; fb < 2; ++fb)                           \
      _Pragma("unroll") for (int i = 0; i < 4; ++i) {                          \
        const float4 v = buf[fb][i];                                           \
        uint2 est; est.x = pack2bf(v.x, v.y); est.y = pack2bf(v.z, v.w);       \
        *(uint2*)(xe + (size_t)(f0 + fb) * 32768 + i * 64) = est;              \
      }                                                                        \
    const float u3a = U3[w * 16 + f0];                                         \
    const float u3b = U3[w * 16 + f0 + 1];                                     \
    float pa0 = 0.f, pa1 = 0.f, pa2 = 0.f, pa3 = 0.f;                          \
    float pb0 = 0.f, pb1 = 0.f, pb2 = 0.f, pb3 = 0.f;                          \
    _Pragma("unroll") for (int i = 0; i < 4; ++i) {                            \
      const float4 va = buf[0][i];                                             \
      const float4 vb = buf[1][i];                                             \
      racc[i][0] += u3a * va.x; racc[i][1] += u3a * va.y;                      \
      racc[i][2] += u3a * va.z; racc[i][3] += u3a * va.w;                      \
      racc[i][0] += u3b * vb.x; racc[i][1] += u3b * vb.y;                      \
      racc[i][2] += u3b * vb.z; racc[i][3] += u3b * vb.w;                      \
      pa0 += u1c[i] * va.x; pa1 += u1c[i] * va.y;                              \
      pa2 += u1c[i] * va.z; pa3 += u1c[i] * va.w;                              \
      pb0 += u1c[i] * vb.x; pb1 += u1c[i] * vb.y;                              \
      pb2 += u1c[i] * vb.z; pb3 += u1c[i] * vb.w;                              \
    }                                                                          \
    pa0 += __shfl_xor(pa0, 16); pa0 += __shfl_xor(pa0, 32);                    \
    pa1 += __shfl_xor(pa1, 16); pa1 += __shfl_xor(pa1, 32);                    \
    pa2 += __shfl_xor(pa2, 16); pa2 += __shfl_xor(pa2, 32);                    \
    pa3 += __shfl_xor(pa3, 16); pa3 += __shfl_xor(pa3, 32);                    \
    pb0 += __shfl_xor(pb0, 16); pb0 += __shfl_xor(pb0, 32);                    \
    pb1 += __shfl_xor(pb1, 16); pb1 += __shfl_xor(pb1, 32);                    \
    pb2 += __shfl_xor(pb2, 16); pb2 += __shfl_xor(pb2, 32);                    \
    pb3 += __shfl_xor(pb3, 16); pb3 += __shfl_xor(pb3, 32);                    \
    if (lane < 16) {                                                           \
      float4 st; st.x = pa0; st.y = pa1; st.z = pa2; st.w = pa3;               \
      *(float4*)&t1part[((size_t)(b * 32 + nc) * 64 + (w * 16 + f0)) * 64 + t0] = st;     \
      float4 st2; st2.x = pb0; st2.y = pb1; st2.z = pb2; st2.w = pb3;          \
      *(float4*)&t1part[((size_t)(b * 32 + nc) * 64 + (w * 16 + f0 + 1)) * 64 + t0] = st2; \
    }                                                                          \
  }

  K1_LOAD(bufA, 0)
#pragma unroll
  for (int gg = 0; gg < 4; ++gg) {
    const int gA = 2 * gg;
    if (gA + 1 < 8) K1_LOAD(bufB, gA + 1)
    K1_PROC(bufA, gA)
    const int gB = 2 * gg + 1;
    if (gB + 1 < 8) K1_LOAD(bufA, gB + 1)
    K1_PROC(bufB, gB)
  }
#undef K1_LOAD
#undef K1_PROC

  // cross-wave reduce for rhs
#pragma unroll
  for (int i = 0; i < 4; ++i) {
    float4 st; st.x = racc[i][0]; st.y = racc[i][1]; st.z = racc[i][2]; st.w = racc[i][3];
    *(float4*)&lds[w][(n_sub * 4 + i) * 64 + t0] = st;
  }
  __syncthreads();
#pragma unroll
  for (int q = 0; q < 4; ++q) {
    const int idx = q * 256 + tid;  // n_local*64 + t
    const float s = lds[0][idx] + lds[1][idx] + lds[2][idx] + lds[3][idx];
    rhs[((size_t)b * N_ + n0 + (idx >> 6)) * T_ + (idx & 63)] = s;
  }
}

// wpart[b,c,f,s] = sum_{n in 64-chunk c} U2[n,f] * rhs[b,n,s]
__global__ __launch_bounds__(256) void k2_w(const float* __restrict__ rhs,
    const float* __restrict__ U2, float* __restrict__ wpart) {
  const int b = blockIdx.x;
  const int c = blockIdx.y;
  const int n0 = c * 64;
  const int tid = threadIdx.x;
  const int s = tid & 63;
  const int fg = tid >> 6;
  __shared__ float lu2[64 * 64];
  __shared__ float lr[64 * 64];
#pragma unroll
  for (int q = 0; q < 16; ++q) {
    const int idx = q * 256 + tid;
    const int i = idx >> 6, cc = idx & 63;
    lu2[idx] = U2[(size_t)(n0 + i) * F_ + cc];
    lr[idx] = rhs[((size_t)b * N_ + n0 + i) * T_ + cc];
  }
  __syncthreads();
  float acc[16];
#pragma unroll
  for (int j = 0; j < 16; ++j) acc[j] = 0.f;
  for (int i = 0; i < 64; ++i) {
    const float rv = lr[i * 64 + s];
#pragma unroll
    for (int j = 0; j < 16; ++j) acc[j] += lu2[i * 64 + fg * 16 + j] * rv;
  }
#pragma unroll
  for (int j = 0; j < 16; ++j)
    wpart[(size_t)(b * 8 + c) * 4096 + (size_t)(fg * 16 + j) * 64 + s] = acc[j];
}

// Collapse partials: t1[b,f,t] = sum_c(32) t1part ; wbf[b,f,s] = sum_c(8) wpart
__global__ __launch_bounds__(256) void kred(const float* __restrict__ t1part,
    const float* __restrict__ wpart, float* __restrict__ t1, float* __restrict__ wbf) {
  const int gid = blockIdx.x * 256 + threadIdx.x;
  if (gid < 131072) {
    const int b = gid >> 12, idx = gid & 4095;
    const float* p = t1part + (size_t)b * 32 * 4096 + idx;
    float sum = 0.f;
#pragma unroll
    for (int c = 0; c < 32; ++c) sum += p[c * 4096];
    t1[gid] = sum;
  } else {
    const int g = gid - 131072;
    const int b = g >> 12, idx = g & 4095;
    const float* p = wpart + (size_t)b * 8 * 4096 + idx;
    float sum = 0.f;
#pragma unroll
    for (int c = 0; c < 8; ++c) sum += p[c * 4096];
    wbf[g] = sum;
  }
}

// Per-batch: product = t1^T w; S = sigmoid(product+be); E = Ve*S; A = softmax_t(E)
__global__ __launch_bounds__(256) void k3_attn(const float* __restrict__ t1,
    const float* __restrict__ wbuf, const float* __restrict__ be,
    const float* __restrict__ Ve, float* __restrict__ Amat) {
  const int b = blockIdx.x;
  const int tid = threadIdx.x;
  const int lane = tid & 63;
  const int tg = tid >> 6;
  __shared__ float bufA[64 * 65];
  __shared__ float bufB[64 * 65];
  __shared__ float red[2][4][64];
#pragma unroll
  for (int q = 0; q < 16; ++q) {
    const int idx = q * 256 + tid;
    const int r = idx >> 6, c = idx & 63;
    bufA[r * 65 + c] = t1[(size_t)b * 4096 + idx];   // [f][t]
    bufB[r * 65 + c] = wbuf[(size_t)b * 4096 + idx]; // [f][s]
  }
  __syncthreads();
  float prod[16];
#pragma unroll
  for (int j = 0; j < 16; ++j) prod[j] = 0.f;
  for (int f = 0; f < 64; ++f) {
    const float wv = bufB[f * 65 + lane];
#pragma unroll
    for (int j = 0; j < 16; ++j) prod[j] += bufA[f * 65 + tg * 16 + j] * wv;
  }
  __syncthreads();
#pragma unroll
  for (int j = 0; j < 16; ++j) {
    const int tt = tg * 16 + j;
    const float v = prod[j] + be[tt * 64 + lane];
    bufA[tt * 65 + lane] = 1.f / (1.f + __expf(-v));
  }
#pragma unroll
  for (int q = 0; q < 16; ++q) {
    const int idx = q * 256 + tid;
    bufB[(idx >> 6) * 65 + (idx & 63)] = Ve[idx];
  }
  __syncthreads();
  float E[16];
#pragma unroll
  for (int j = 0; j < 16; ++j) E[j] = 0.f;
  for (int s = 0; s < 64; ++s) {
    const float sv = bufA[s * 65 + lane];
#pragma unroll
    for (int j = 0; j < 16; ++j) E[j] += bufB[(tg * 16 + j) * 65 + s] * sv;
  }
  float m = E[0];
#pragma unroll
  for (int j = 1; j < 16; ++j) m = fmaxf(m, E[j]);
  red[0][tg][lane] = m;
  __syncthreads();
  m = fmaxf(fmaxf(red[0][0][lane], red[0][1][lane]),
            fmaxf(red[0][2][lane], red[0][3][lane]));
  float se = 0.f;
  float ex[16];
#pragma unroll
  for (int j = 0; j < 16; ++j) { ex[j] = __expf(E[j] - m); se += ex[j]; }
  red[1][tg][lane] = se;
  __syncthreads();
  const float gs = red[1][0][lane] + red[1][1][lane] + red[1][2][lane] + red[1][3][lane];
  const float inv = 1.f / gs;
#pragma unroll
  for (int j = 0; j < 16; ++j) {
    const int tt = tg * 16 + j;
    Amat[(size_t)b * 4096 + tt * 64 + lane] = ex[j] * inv;
  }
}

// out[b,fn,s] = sum_t xbf[b,fn,t] * A[b,t,s] via bf16 MFMA. Wave = 16 rows x 64 cols.
// Reads the bf16 echo: half the read bytes of fp32 x, no f2bf on the A-path.
__global__ __launch_bounds__(256) void k4_out(const unsigned short* __restrict__ xbf,
    const float* __restrict__ Amat, float* __restrict__ out) {
  const int b = blockIdx.x;
  const int chunk = blockIdx.y;
  const int tid = threadIdx.x;
  const int wv = tid >> 6;
  const int l = tid & 63;
  __shared__ float lA[64 * 65];
  const float* Ab = Amat + (size_t)b * 4096;
#pragma unroll
  for (int q = 0; q < 16; ++q) {
    const int idx = q * 256 + tid;
    lA[(idx >> 6) * 65 + (idx & 63)] = Ab[idx];
  }
  __syncthreads();

  const int krow0 = (l >> 4) * 8;
  const int colb = l & 15;
  bf16x8 Bf[4][2];
#pragma unroll
  for (int nt = 0; nt < 4; ++nt)
#pragma unroll
    for (int kh = 0; kh < 2; ++kh) {
      bf16x8 fr;
#pragma unroll
      for (int j = 0; j < 8; ++j) {
        const int k = kh * 32 + krow0 + j;
        fr[j] = (short)f2bf(lA[k * 65 + nt * 16 + colb]);
      }
      Bf[nt][kh] = fr;
    }

  const unsigned short* Xb = xbf + (size_t)b * (F_ * (size_t)N_ * T_);
  float* Ob = out + (size_t)b * (F_ * (size_t)N_ * T_);
  const int rl = l & 15;
  const int c0 = (l >> 4) * 8;

  for (int it = 0; it < 4; ++it) {
    const int tile = chunk * 16 + wv * 4 + it;  // 0..2047
    const int r = tile * 16 + rl;
    const unsigned short* xr = Xb + (size_t)r * T_;
    const bf16x8 a0 = *(const bf16x8*)(xr + c0);       // k = 0..31 slice
    const bf16x8 a1 = *(const bf16x8*)(xr + 32 + c0);  // k = 32..63 slice

    const int rowb = tile * 16 + (l >> 4) * 4;
#pragma unroll
    for (int nt = 0; nt < 4; ++nt) {
      f32x4 c = {0.f, 0.f, 0.f, 0.f};
      c = __builtin_amdgcn_mfma_f32_16x16x32_bf16(a0, Bf[nt][0], c, 0, 0, 0);
      c = __builtin_amdgcn_mfma_f32_16x16x32_bf16(a1, Bf[nt][1], c, 0, 0, 0);
#pragma unroll
      for (int j = 0; j < 4; ++j)
        Ob[(size_t)(rowb + j) * T_ + nt * 16 + colb] = c[j];
    }
  }
}

extern "C" void kernel_launch(void* const* d_in, const int* in_sizes, int n_in,
                              void* d_out, int out_size, void* d_ws, size_t ws_size,
                              hipStream_t stream) {
  const float* x  = (const float*)d_in[0];
  const float* U1 = (const float*)d_in[1];
  const float* U2 = (const float*)d_in[2];
  const float* U3 = (const float*)d_in[3];
  const float* be = (const float*)d_in[4];
  const float* Ve = (const float*)d_in[5];
  float* out = (float*)d_out;
  float* ws = (float*)d_ws;

  float* t1part = ws;                    // 32*32*4096 = 4,194,304 floats (16 MB)
  float* rhs    = t1part + 4194304;      // 32*512*64  = 1,048,576 floats (4 MB)
  float* wpart  = rhs + 1048576;         // 32*8*4096  = 1,048,576 floats (4 MB)
  float* t1     = wpart + 1048576;       // 131072 floats
  float* wbf    = t1 + 131072;           // 131072 floats
  float* Amat   = wbf + 131072;          // 131072 floats
  unsigned short* xbf = (unsigned short*)(Amat + 131072);  // 67,108,864 bf16 (128 MB)

  k1_reduce<<<dim3(32, 32), 256, 0, stream>>>(x, U1, U3, t1part, rhs, xbf);
  k2_w<<<dim3(32, 8), 256, 0, stream>>>(rhs, U2, wpart);
  kred<<<1024, 256, 0, stream>>>(t1part, wpart, t1, wbf);
  k3_attn<<<32, 256, 0, stream>>>(t1, wbf, be, Ve, Amat);
  k4_out<<<dim3(32, 128), 256, 0, stream>>>(xbf, Amat, out);
}

// Round 11
// 193.589 us; speedup vs baseline: 1.7388x; 1.0828x over previous
//
#include <hip/hip_runtime.h>
#include <hip/hip_bf16.h>

#define B_ 32
#define F_ 64
#define N_ 512
#define T_ 64

typedef __attribute__((ext_vector_type(8))) short bf16x8;
typedef __attribute__((ext_vector_type(4))) float f32x4;

__device__ __forceinline__ unsigned short f2bf(float f) {
  union { float f; unsigned int u; } v; v.f = f;
  unsigned int u = v.u;
  unsigned int r = (u + 0x7FFFu + ((u >> 16) & 1u)) >> 16;
  return (unsigned short)r;
}

// Pass 1 over x. Block=(b, 16-n chunk), 1024 blocks. Wave w owns f in [16w,16w+16).
// VGPR float4 loads, explicit 2-f-group ping-pong prefetch (8 loads in flight/wave,
// issued BEFORE the current group's FMA+shuffle epilogue).
//   rhs[b,n,t]       = sum_f U3[f]*x[b,f,n,t]   (cross-wave LDS reduce)
//   t1part[b,nc,f,t] = sum_{n in chunk} U1[n]*x (shuffle-reduced partial)
__global__ __launch_bounds__(256) void k1_reduce(const float* __restrict__ x,
    const float* __restrict__ U1, const float* __restrict__ U3,
    float* __restrict__ t1part, float* __restrict__ rhs) {
  const int b = blockIdx.x;
  const int nc = blockIdx.y;
  const int n0 = nc * 16;
  const int tid = threadIdx.x;
  const int w = tid >> 6;
  const int lane = tid & 63;
  const int n_sub = lane >> 4;
  const int t0 = (lane & 15) * 4;

  __shared__ float lds[4][1024];

  // wave base: x[b, w*16, n0, 0]; f-slab j at +j*32768 floats
  const float* xw = x + ((size_t)(b * F_ + w * 16) * N_ + n0) * T_;
  const int loff = n_sub * 256 + t0;  // (n_sub*4)*64 + t0

  float u1c[4];
#pragma unroll
  for (int i = 0; i < 4; ++i) u1c[i] = U1[n0 + n_sub * 4 + i];

  float racc[4][4];
#pragma unroll
  for (int i = 0; i < 4; ++i)
#pragma unroll
    for (int k = 0; k < 4; ++k) racc[i][k] = 0.f;

  float4 bufA[2][4], bufB[2][4];

  // group g covers f = 2g, 2g+1 (g = 0..7). Load group into a buffer:
#define K1_LOAD(buf, g)                                                        \
  _Pragma("unroll") for (int i = 0; i < 4; ++i) {                              \
    buf[0][i] = *(const float4*)(xw + (size_t)(2 * (g)) * 32768 + loff + i * 64);     \
    buf[1][i] = *(const float4*)(xw + (size_t)(2 * (g) + 1) * 32768 + loff + i * 64); \
  }

  // Process group g held in buf (f0 = 2g): FMAs + shuffle-reduce + t1part store.
#define K1_PROC(buf, g)                                                        \
  {                                                                            \
    const int f0 = 2 * (g);                                                    \
    const float u3a = U3[w * 16 + f0];                                         \
    const float u3b = U3[w * 16 + f0 + 1];                                     \
    float pa0 = 0.f, pa1 = 0.f, pa2 = 0.f, pa3 = 0.f;                          \
    float pb0 = 0.f, pb1 = 0.f, pb2 = 0.f, pb3 = 0.f;                          \
    _Pragma("unroll") for (int i = 0; i < 4; ++i) {                            \
      const float4 va = buf[0][i];                                            \
      const float4 vb = buf[1][i];                                            \
      racc[i][0] += u3a * va.x; racc[i][1] += u3a * va.y;                      \
      racc[i][2] += u3a * va.z; racc[i][3] += u3a * va.w;                      \
      racc[i][0] += u3b * vb.x; racc[i][1] += u3b * vb.y;                      \
      racc[i][2] += u3b * vb.z; racc[i][3] += u3b * vb.w;                      \
      pa0 += u1c[i] * va.x; pa1 += u1c[i] * va.y;                              \
      pa2 += u1c[i] * va.z; pa3 += u1c[i] * va.w;                              \
      pb0 += u1c[i] * vb.x; pb1 += u1c[i] * vb.y;                              \
      pb2 += u1c[i] * vb.z; pb3 += u1c[i] * vb.w;                              \
    }                                                                          \
    pa0 += __shfl_xor(pa0, 16); pa0 += __shfl_xor(pa0, 32);                    \
    pa1 += __shfl_xor(pa1, 16); pa1 += __shfl_xor(pa1, 32);                    \
    pa2 += __shfl_xor(pa2, 16); pa2 += __shfl_xor(pa2, 32);                    \
    pa3 += __shfl_xor(pa3, 16); pa3 += __shfl_xor(pa3, 32);                    \
    pb0 += __shfl_xor(pb0, 16); pb0 += __shfl_xor(pb0, 32);                    \
    pb1 += __shfl_xor(pb1, 16); pb1 += __shfl_xor(pb1, 32);                    \
    pb2 += __shfl_xor(pb2, 16); pb2 += __shfl_xor(pb2, 32);                    \
    pb3 += __shfl_xor(pb3, 16); pb3 += __shfl_xor(pb3, 32);                    \
    if (lane < 16) {                                                           \
      float4 st; st.x = pa0; st.y = pa1; st.z = pa2; st.w = pa3;               \
      *(float4*)&t1part[((size_t)(b * 32 + nc) * 64 + (w * 16 + f0)) * 64 + t0] = st;     \
      float4 st2; st2.x = pb0; st2.y = pb1; st2.z = pb2; st2.w = pb3;          \
      *(float4*)&t1part[((size_t)(b * 32 + nc) * 64 + (w * 16 + f0 + 1)) * 64 + t0] = st2; \
    }                                                                          \
  }

  K1_LOAD(bufA, 0)
#pragma unroll
  for (int gg = 0; gg < 4; ++gg) {
    const int gA = 2 * gg;
    if (gA + 1 < 8) K1_LOAD(bufB, gA + 1)   // prefetch BEFORE current epilogue
    K1_PROC(bufA, gA)
    const int gB = 2 * gg + 1;
    if (gB + 1 < 8) K1_LOAD(bufA, gB + 1)
    K1_PROC(bufB, gB)
  }
#undef K1_LOAD
#undef K1_PROC

  // cross-wave reduce for rhs
#pragma unroll
  for (int i = 0; i < 4; ++i) {
    float4 st; st.x = racc[i][0]; st.y = racc[i][1]; st.z = racc[i][2]; st.w = racc[i][3];
    *(float4*)&lds[w][(n_sub * 4 + i) * 64 + t0] = st;
  }
  __syncthreads();
#pragma unroll
  for (int q = 0; q < 4; ++q) {
    const int idx = q * 256 + tid;  // n_local*64 + t
    const float s = lds[0][idx] + lds[1][idx] + lds[2][idx] + lds[3][idx];
    rhs[((size_t)b * N_ + n0 + (idx >> 6)) * T_ + (idx & 63)] = s;
  }
}

// wpart[b,c,f,s] = sum_{n in 64-chunk c} U2[n,f] * rhs[b,n,s]
__global__ __launch_bounds__(256) void k2_w(const float* __restrict__ rhs,
    const float* __restrict__ U2, float* __restrict__ wpart) {
  const int b = blockIdx.x;
  const int c = blockIdx.y;
  const int n0 = c * 64;
  const int tid = threadIdx.x;
  const int s = tid & 63;
  const int fg = tid >> 6;
  __shared__ float lu2[64 * 64];
  __shared__ float lr[64 * 64];
#pragma unroll
  for (int q = 0; q < 16; ++q) {
    const int idx = q * 256 + tid;
    const int i = idx >> 6, cc = idx & 63;
    lu2[idx] = U2[(size_t)(n0 + i) * F_ + cc];
    lr[idx] = rhs[((size_t)b * N_ + n0 + i) * T_ + cc];
  }
  __syncthreads();
  float acc[16];
#pragma unroll
  for (int j = 0; j < 16; ++j) acc[j] = 0.f;
  for (int i = 0; i < 64; ++i) {
    const float rv = lr[i * 64 + s];
#pragma unroll
    for (int j = 0; j < 16; ++j) acc[j] += lu2[i * 64 + fg * 16 + j] * rv;
  }
#pragma unroll
  for (int j = 0; j < 16; ++j)
    wpart[(size_t)(b * 8 + c) * 4096 + (size_t)(fg * 16 + j) * 64 + s] = acc[j];
}

// Collapse partials: t1[b,f,t] = sum_c(32) t1part ; wbf[b,f,s] = sum_c(8) wpart
__global__ __launch_bounds__(256) void kred(const float* __restrict__ t1part,
    const float* __restrict__ wpart, float* __restrict__ t1, float* __restrict__ wbf) {
  const int gid = blockIdx.x * 256 + threadIdx.x;
  if (gid < 131072) {
    const int b = gid >> 12, idx = gid & 4095;
    const float* p = t1part + (size_t)b * 32 * 4096 + idx;
    float sum = 0.f;
#pragma unroll
    for (int c = 0; c < 32; ++c) sum += p[c * 4096];
    t1[gid] = sum;
  } else {
    const int g = gid - 131072;
    const int b = g >> 12, idx = g & 4095;
    const float* p = wpart + (size_t)b * 8 * 4096 + idx;
    float sum = 0.f;
#pragma unroll
    for (int c = 0; c < 8; ++c) sum += p[c * 4096];
    wbf[g] = sum;
  }
}

// Per-batch: product = t1^T w; S = sigmoid(product+be); E = Ve*S; A = softmax_t(E)
__global__ __launch_bounds__(256) void k3_attn(const float* __restrict__ t1,
    const float* __restrict__ wbuf, const float* __restrict__ be,
    const float* __restrict__ Ve, float* __restrict__ Amat) {
  const int b = blockIdx.x;
  const int tid = threadIdx.x;
  const int lane = tid & 63;
  const int tg = tid >> 6;
  __shared__ float bufA[64 * 65];
  __shared__ float bufB[64 * 65];
  __shared__ float red[2][4][64];
#pragma unroll
  for (int q = 0; q < 16; ++q) {
    const int idx = q * 256 + tid;
    const int r = idx >> 6, c = idx & 63;
    bufA[r * 65 + c] = t1[(size_t)b * 4096 + idx];   // [f][t]
    bufB[r * 65 + c] = wbuf[(size_t)b * 4096 + idx]; // [f][s]
  }
  __syncthreads();
  float prod[16];
#pragma unroll
  for (int j = 0; j < 16; ++j) prod[j] = 0.f;
  for (int f = 0; f < 64; ++f) {
    const float wv = bufB[f * 65 + lane];
#pragma unroll
    for (int j = 0; j < 16; ++j) prod[j] += bufA[f * 65 + tg * 16 + j] * wv;
  }
  __syncthreads();
#pragma unroll
  for (int j = 0; j < 16; ++j) {
    const int tt = tg * 16 + j;
    const float v = prod[j] + be[tt * 64 + lane];
    bufA[tt * 65 + lane] = 1.f / (1.f + __expf(-v));
  }
#pragma unroll
  for (int q = 0; q < 16; ++q) {
    const int idx = q * 256 + tid;
    bufB[(idx >> 6) * 65 + (idx & 63)] = Ve[idx];
  }
  __syncthreads();
  float E[16];
#pragma unroll
  for (int j = 0; j < 16; ++j) E[j] = 0.f;
  for (int s = 0; s < 64; ++s) {
    const float sv = bufA[s * 65 + lane];
#pragma unroll
    for (int j = 0; j < 16; ++j) E[j] += bufB[(tg * 16 + j) * 65 + s] * sv;
  }
  float m = E[0];
#pragma unroll
  for (int j = 1; j < 16; ++j) m = fmaxf(m, E[j]);
  red[0][tg][lane] = m;
  __syncthreads();
  m = fmaxf(fmaxf(red[0][0][lane], red[0][1][lane]),
            fmaxf(red[0][2][lane], red[0][3][lane]));
  float se = 0.f;
  float ex[16];
#pragma unroll
  for (int j = 0; j < 16; ++j) { ex[j] = __expf(E[j] - m); se += ex[j]; }
  red[1][tg][lane] = se;
  __syncthreads();
  const float gs = red[1][0][lane] + red[1][1][lane] + red[1][2][lane] + red[1][3][lane];
  const float inv = 1.f / gs;
#pragma unroll
  for (int j = 0; j < 16; ++j) {
    const int tt = tg * 16 + j;
    Amat[(size_t)b * 4096 + tt * 64 + lane] = ex[j] * inv;
  }
}

// out[b,fn,s] = sum_t x[b,fn,t] * A[b,t,s] via bf16 MFMA. Wave = 16 rows x 64 cols.
__global__ __launch_bounds__(256) void k4_out(const float* __restrict__ x,
    const float* __restrict__ Amat, float* __restrict__ out) {
  const int b = blockIdx.x;
  const int chunk = blockIdx.y;
  const int tid = threadIdx.x;
  const int wv = tid >> 6;
  const int l = tid & 63;
  __shared__ float lA[64 * 65];
  const float* Ab = Amat + (size_t)b * 4096;
#pragma unroll
  for (int q = 0; q < 16; ++q) {
    const int idx = q * 256 + tid;
    lA[(idx >> 6) * 65 + (idx & 63)] = Ab[idx];
  }
  __syncthreads();

  const int krow0 = (l >> 4) * 8;
  const int colb = l & 15;
  bf16x8 Bf[4][2];
#pragma unroll
  for (int nt = 0; nt < 4; ++nt)
#pragma unroll
    for (int kh = 0; kh < 2; ++kh) {
      bf16x8 fr;
#pragma unroll
      for (int j = 0; j < 8; ++j) {
        const int k = kh * 32 + krow0 + j;
        fr[j] = (short)f2bf(lA[k * 65 + nt * 16 + colb]);
      }
      Bf[nt][kh] = fr;
    }

  const float* Xb = x + (size_t)b * (F_ * (size_t)N_ * T_);
  float* Ob = out + (size_t)b * (F_ * (size_t)N_ * T_);
  const int rl = l & 15;
  const int c0 = (l >> 4) * 8;

  for (int it = 0; it < 4; ++it) {
    const int tile = chunk * 16 + wv * 4 + it;  // 0..2047
    const int r = tile * 16 + rl;
    const float* xr = Xb + (size_t)r * T_;
    const float4 v0 = *(const float4*)(xr + c0);
    const float4 v1 = *(const float4*)(xr + c0 + 4);
    const float4 v2 = *(const float4*)(xr + 32 + c0);
    const float4 v3 = *(const float4*)(xr + 32 + c0 + 4);
    bf16x8 a0, a1;
    a0[0] = (short)f2bf(v0.x); a0[1] = (short)f2bf(v0.y);
    a0[2] = (short)f2bf(v0.z); a0[3] = (short)f2bf(v0.w);
    a0[4] = (short)f2bf(v1.x); a0[5] = (short)f2bf(v1.y);
    a0[6] = (short)f2bf(v1.z); a0[7] = (short)f2bf(v1.w);
    a1[0] = (short)f2bf(v2.x); a1[1] = (short)f2bf(v2.y);
    a1[2] = (short)f2bf(v2.z); a1[3] = (short)f2bf(v2.w);
    a1[4] = (short)f2bf(v3.x); a1[5] = (short)f2bf(v3.y);
    a1[6] = (short)f2bf(v3.z); a1[7] = (short)f2bf(v3.w);

    const int rowb = tile * 16 + (l >> 4) * 4;
#pragma unroll
    for (int nt = 0; nt < 4; ++nt) {
      f32x4 c = {0.f, 0.f, 0.f, 0.f};
      c = __builtin_amdgcn_mfma_f32_16x16x32_bf16(a0, Bf[nt][0], c, 0, 0, 0);
      c = __builtin_amdgcn_mfma_f32_16x16x32_bf16(a1, Bf[nt][1], c, 0, 0, 0);
#pragma unroll
      for (int j = 0; j < 4; ++j)
        Ob[(size_t)(rowb + j) * T_ + nt * 16 + colb] = c[j];
    }
  }
}

extern "C" void kernel_launch(void* const* d_in, const int* in_sizes, int n_in,
                              void* d_out, int out_size, void* d_ws, size_t ws_size,
                              hipStream_t stream) {
  const float* x  = (const float*)d_in[0];
  const float* U1 = (const float*)d_in[1];
  const float* U2 = (const float*)d_in[2];
  const float* U3 = (const float*)d_in[3];
  const float* be = (const float*)d_in[4];
  const float* Ve = (const float*)d_in[5];
  float* out = (float*)d_out;
  float* ws = (float*)d_ws;

  float* t1part = ws;                    // 32*32*4096 = 4,194,304 floats (16 MB)
  float* rhs    = t1part + 4194304;      // 32*512*64  = 1,048,576 floats (4 MB)
  float* wpart  = rhs + 1048576;         // 32*8*4096  = 1,048,576 floats (4 MB)
  float* t1     = wpart + 1048576;       // 131072 floats
  float* wbf    = t1 + 131072;           // 131072 floats
  float* Amat   = wbf + 131072;          // 131072 floats

  k1_reduce<<<dim3(32, 32), 256, 0, stream>>>(x, U1, U3, t1part, rhs);
  k2_w<<<dim3(32, 8), 256, 0, stream>>>(rhs, U2, wpart);
  kred<<<1024, 256, 0, stream>>>(t1part, wpart, t1, wbf);
  k3_attn<<<32, 256, 0, stream>>>(t1, wbf, be, Ve, Amat);
  k4_out<<<dim3(32, 128), 256, 0, stream>>>(x, Amat, out);
}